// Round 1
// baseline (141.581 us; speedup 1.0000x reference)
//
#include <hip/hip_runtime.h>
#include <math.h>

#define V   4096
#define NB  8
#define TPB 256

// One block = (query chunk of 256 points, batch n, direction z).
// Stages the entire opposite ("ref") cloud in LDS (48KB coords + 16KB |r|^2),
// each thread scans all 4096 refs for its one query point via broadcast
// ds_read_b128, tracking min of (|r|^2 - 2 q.r) in 4 accumulators.
// Final per-query squared min = q2 + min, clamped at 0 (cancellation guard).
// Wave max-reduce, then one uint-bits atomicMax per wave into best[n].
__global__ __launch_bounds__(TPB) void hausdorff_dir(
    const float* __restrict__ x, const float* __restrict__ y,
    unsigned int* __restrict__ best)
{
    __shared__ float4 s4[3 * V / 4];   // 48 KB packed ref coords
    __shared__ float  sr2[V];          // 16 KB |r|^2

    const int n = blockIdx.y;
    const float* qb = (blockIdx.z == 0 ? x : y) + (size_t)n * (3 * V);
    const float* rb = (blockIdx.z == 0 ? y : x) + (size_t)n * (3 * V);
    const int t = threadIdx.x;

    // Stage refs into LDS, fully coalesced float4 loads.
    const float4* g4 = (const float4*)rb;
    #pragma unroll
    for (int k = 0; k < (3 * V / 4) / TPB; ++k)   // 12 iters
        s4[k * TPB + t] = g4[k * TPB + t];
    __syncthreads();

    // |r|^2 pass. Lane i reads floats at 3*p stride: bank (3i)%32,
    // gcd(3,32)=1 -> conflict-free.
    const float* s = (const float*)s4;
    #pragma unroll
    for (int k = 0; k < V / TPB; ++k) {           // 16 iters
        int p = k * TPB + t;
        float rx = s[3 * p], ry = s[3 * p + 1], rz = s[3 * p + 2];
        sr2[p] = rx * rx + ry * ry + rz * rz;
    }

    // Query point (once per thread).
    const int qi = blockIdx.x * TPB + t;
    const float qx = qb[3 * qi], qy = qb[3 * qi + 1], qz = qb[3 * qi + 2];
    const float q2 = qx * qx + qy * qy + qz * qz;
    __syncthreads();

    // Main loop: 4 points per iter = 4 broadcast ds_read_b128 + 20 VALU.
    float m0 = 3.0e38f, m1 = 3.0e38f, m2 = 3.0e38f, m3 = 3.0e38f;
    const float4* sr2_4 = (const float4*)sr2;
    #pragma unroll 2
    for (int j4 = 0; j4 < V / 4; ++j4) {
        float4 p0 = s4[3 * j4 + 0];
        float4 p1 = s4[3 * j4 + 1];
        float4 p2 = s4[3 * j4 + 2];
        float4 r2 = sr2_4[j4];
        float t0 = qx * p0.x + qy * p0.y + qz * p0.z;
        float t1 = qx * p0.w + qy * p1.x + qz * p1.y;
        float t2 = qx * p1.z + qy * p1.w + qz * p2.x;
        float t3 = qx * p2.y + qy * p2.z + qz * p2.w;
        m0 = fminf(m0, fmaf(-2.0f, t0, r2.x));
        m1 = fminf(m1, fmaf(-2.0f, t1, r2.y));
        m2 = fminf(m2, fmaf(-2.0f, t2, r2.z));
        m3 = fminf(m3, fmaf(-2.0f, t3, r2.w));
    }
    float m = fminf(fminf(m0, m1), fminf(m2, m3));
    m = fmaxf(q2 + m, 0.0f);   // clamp: guards sqrt(negative) from cancellation

    // Wave (64-lane) max-reduce, one atomic per wave.
    #pragma unroll
    for (int off = 32; off > 0; off >>= 1)
        m = fmaxf(m, __shfl_xor(m, off));
    if ((t & 63) == 0)
        atomicMax(&best[n], __float_as_uint(m));
}

__global__ void hausdorff_finalize(const unsigned int* __restrict__ best,
                                   float* __restrict__ out)
{
    if (threadIdx.x == 0) {
        float sum = 0.0f;
        #pragma unroll
        for (int n = 0; n < NB; ++n)
            sum += sqrtf(__uint_as_float(best[n]));
        out[0] = sum * (1.0f / NB);
    }
}

extern "C" void kernel_launch(void* const* d_in, const int* in_sizes, int n_in,
                              void* d_out, int out_size, void* d_ws, size_t ws_size,
                              hipStream_t stream)
{
    const float* x = (const float*)d_in[0];
    const float* y = (const float*)d_in[1];
    unsigned int* best = (unsigned int*)d_ws;

    // Workspace is poisoned to 0xAA before every launch; zero the 8 max cells.
    hipMemsetAsync(d_ws, 0, NB * sizeof(unsigned int), stream);

    dim3 grid(V / TPB, NB, 2);
    hausdorff_dir<<<grid, TPB, 0, stream>>>(x, y, best);
    hausdorff_finalize<<<1, 64, 0, stream>>>(best, (float*)d_out);
}